// Round 13
// baseline (263.440 us; speedup 1.0000x reference)
//
#include <hip/hip_runtime.h>

#define IN_DIM   128
#define NH       8
#define HD       16
#define OUTD     128   // NH*HD
#define QKVD     384   // Q|K|V per node, bf16
#define SH       7     // coarse bucket = 128 nodes
#define NSORTB   128   // sort blocks (private regions) -> 33.2KB LDS
#define GRID     1024

typedef unsigned short ushort_t;
typedef unsigned int   uint_t;
typedef __bf16 bf16x8 __attribute__((ext_vector_type(8)));
typedef float  f32x4  __attribute__((ext_vector_type(4)));

__device__ __forceinline__ float bf2f(ushort_t u) {
    return __uint_as_float(((uint_t)u) << 16);
}
__device__ __forceinline__ ushort_t f2bf(float f) {
    uint_t u = __float_as_uint(f);
    u += 0x7FFFu + ((u >> 16) & 1u);      // RNE
    return (ushort_t)(u >> 16);
}

// ---------------------------------------------------------------------------
// prep_w: W[k][c] fp32 (3 mats) -> Wt[col][k] bf16, col in [0,384).
// ---------------------------------------------------------------------------
__global__ __launch_bounds__(256) void prep_w(
    const float* __restrict__ Wq, const float* __restrict__ Wk,
    const float* __restrict__ Wv, ushort_t* __restrict__ Wt)
{
    __shared__ float ld[32][33];
    int mat  = blockIdx.x >> 4;
    int tile = blockIdx.x & 15;
    int k0 = (tile >> 2) * 32, c0 = (tile & 3) * 32;
    const float* W = (mat == 0) ? Wq : (mat == 1) ? Wk : Wv;
    int t = threadIdx.x;
    {
        int k = t >> 3, c4 = (t & 7) * 4;
        float4 f = *(const float4*)&W[(size_t)(k0 + k) * 128 + c0 + c4];
        ld[k][c4 + 0] = f.x; ld[k][c4 + 1] = f.y;
        ld[k][c4 + 2] = f.z; ld[k][c4 + 3] = f.w;
    }
    __syncthreads();
    {
        int c = t >> 3, kg = (t & 7) * 4;
        union { ushort_t h[4]; uint2 u; } o;
        o.h[0] = f2bf(ld[kg + 0][c]); o.h[1] = f2bf(ld[kg + 1][c]);
        o.h[2] = f2bf(ld[kg + 2][c]); o.h[3] = f2bf(ld[kg + 3][c]);
        *(uint2*)&Wt[((size_t)(mat * 128 + c0 + c)) * 128 + k0 + kg] = o.u;
    }
}

// ---------------------------------------------------------------------------
// FAT kernel: 1024 blocks x 384 thr.
//  - blocks [0,128): coarse counting sort of 6250-edge chunks (r10-proven).
//  - blocks [128,1024): persistent bf16 MFMA GEMM over 64-row tiles.
//    Register prefetch of the NEXT tile's x-chunks issued right after the
//    current tile's LDS staging — loads stay in flight across the MFMA and
//    epilogue phases (Little's-law fix for the 2.1 TB/s plateau).
// ---------------------------------------------------------------------------
__global__ __launch_bounds__(384, 3) void fat_gemm_sort(
    const float* __restrict__ x, const ushort_t* __restrict__ Wt,
    const float* __restrict__ bq, const float* __restrict__ bk,
    const float* __restrict__ bv, ushort_t* __restrict__ qkv,
    const int* __restrict__ ei, int* __restrict__ aux,
    uint_t* __restrict__ regions,
    int N, int E, int ntiles, int NBC, int CH)
{
    __shared__ __align__(16) char smem[33192];

    if (blockIdx.x < NSORTB) {
        // ================= sort path (r10-proven) =================
        uint_t* recs = (uint_t*)smem;                 // 6250 * 4 = 25000 B
        int* hist    = (int*)(smem + 25000);          // 1024 * 4
        int* scn     = (int*)(smem + 29096);          // 1024 * 4
        const int tid = threadIdx.x;
        const int blk = blockIdx.x;
        const int e0g = blk * CH;
        const int e1g = min(E, e0g + CH);
        const int m   = e1g - e0g;

        for (int i = tid; i < 1024; i += 384) hist[i] = 0;
        __syncthreads();
        for (int e = e0g + tid; e < e1g; e += 384)
            atomicAdd(&hist[ei[E + e] >> SH], 1);
        __syncthreads();
        if (tid < 64) {           // wave 0: exclusive scan of 1024 bins
            int base16 = tid * 16;
            int loc[16]; int s = 0;
#pragma unroll
            for (int i = 0; i < 16; i++) { loc[i] = s; s += hist[base16 + i]; }
            int incl = s;
            for (int off = 1; off < 64; off <<= 1) {
                int t = __shfl_up(incl, off);
                if (tid >= off) incl += t;
            }
            int cexcl = incl - s;
#pragma unroll
            for (int i = 0; i < 16; i++) scn[base16 + i] = cexcl + loc[i];
        }
        __syncthreads();
        for (int b = tid; b < NBC; b += 384) aux[b * NSORTB + blk] = scn[b];
        if (tid == 0) aux[NBC * NSORTB + blk] = m;   // sentinel row
        __syncthreads();
        for (int e = e0g + tid; e < e1g; e += 384) {
            int d = ei[E + e];
            int src = ei[e];
            int slot = atomicAdd(&scn[d >> SH], 1);
            recs[slot] = (uint_t)src | ((uint_t)(d & 127) << 20);
        }
        __syncthreads();
        for (int s = tid; s < m; s += 384)
            regions[(size_t)blk * CH + s] = recs[s];
        return;
    }

    // ================= gemm path (+ next-tile register prefetch) ===========
    ushort_t* sh = (ushort_t*)smem;   // uses 16640 B of the 33192

    const int tid  = threadIdx.x;
    const int w    = tid >> 6;        // wave 0..5
    const int quad = (tid >> 4) & 3;
    const int l15  = tid & 15;
    const int colg = w << 6;          // col base 0..320

    bf16x8 bfr[4][4];
#pragma unroll
    for (int kt = 0; kt < 4; kt++)
#pragma unroll
        for (int cs = 0; cs < 4; cs++) {
            int col = colg + cs * 16 + l15;
            bfr[kt][cs] = *(const bf16x8*)&Wt[(size_t)col * 128 + kt * 32 + quad * 8];
        }

    const int mat = w >> 1;           // 0=Q,1=K,2=V
    const float* Bp = (mat == 0) ? bq : (mat == 1) ? bk : bv;
    float bias[4];
#pragma unroll
    for (int cs = 0; cs < 4; cs++)
        bias[cs] = Bp[((w & 1) << 6) + cs * 16 + l15];

    const int gstride = (int)gridDim.x - NSORTB;
    const int tile0   = (int)blockIdx.x - NSORTB;

    // per-thread staging chunks: c0=tid, c1=tid+384, c2=tid+768 (if <1024)
    const int c0 = tid, c1 = tid + 384, c2 = tid + 768;
    const bool has2 = (c2 < 1024);
    float4 pa0, pb0, pa1, pb1, pa2, pb2;

#define PFC(ch, fa, fb, r0_)                                                \
    {                                                                       \
        int row = (ch) >> 4, kc = (ch) & 15;                                \
        int grow = (r0_) + row; if (grow > N - 1) grow = N - 1;             \
        const float* xp = x + (size_t)grow * IN_DIM + kc * 8;               \
        fa = *(const float4*)xp; fb = *(const float4*)(xp + 4);             \
    }
#define PF(tilev)                                                           \
    {                                                                       \
        int r0_ = (tilev) * 64;                                             \
        PFC(c0, pa0, pb0, r0_);                                             \
        PFC(c1, pa1, pb1, r0_);                                             \
        if (has2) PFC(c2, pa2, pb2, r0_);                                   \
    }
#define WRCH(ch, fa, fb)                                                    \
    {                                                                       \
        int row = (ch) >> 4, kc = (ch) & 15;                                \
        union { ushort_t h[8]; uint4 u; } tt;                               \
        tt.h[0] = f2bf(fa.x); tt.h[1] = f2bf(fa.y);                         \
        tt.h[2] = f2bf(fa.z); tt.h[3] = f2bf(fa.w);                         \
        tt.h[4] = f2bf(fb.x); tt.h[5] = f2bf(fb.y);                         \
        tt.h[6] = f2bf(fb.z); tt.h[7] = f2bf(fb.w);                         \
        *(uint4*)&sh[(kc * 65 + row) * 8] = tt.u;                           \
    }

    if (tile0 < ntiles) PF(tile0);    // prologue prefetch

    for (int tile = tile0; tile < ntiles; tile += gstride) {
        const int row0 = tile * 64;
        __syncthreads();   // B1: sh free (prev epilogue readers done)

        // stage: convert prefetched regs -> LDS (waits on their loads)
        WRCH(c0, pa0, pb0);
        WRCH(c1, pa1, pb1);
        if (has2) WRCH(c2, pa2, pb2);

        // issue NEXT tile's loads now — they fly across MFMA + epilogue
        int nt = tile + gstride;
        if (nt < ntiles) PF(nt);

        __syncthreads();   // B2: staging complete

        f32x4 acc[4][4];
#pragma unroll
        for (int r = 0; r < 4; r++)
#pragma unroll
            for (int cs = 0; cs < 4; cs++) acc[r][cs] = (f32x4){0.f, 0.f, 0.f, 0.f};

#pragma unroll
        for (int kt = 0; kt < 4; kt++) {
            int kc = kt * 4 + quad;
            bf16x8 af[4];
#pragma unroll
            for (int r = 0; r < 4; r++)
                af[r] = *(const bf16x8*)&sh[(kc * 65 + r * 16 + l15) * 8];
#pragma unroll
            for (int r = 0; r < 4; r++)
#pragma unroll
                for (int cs = 0; cs < 4; cs++)
                    acc[r][cs] = __builtin_amdgcn_mfma_f32_16x16x32_bf16(
                        af[r], bfr[kt][cs], acc[r][cs], 0, 0, 0);
        }

#define EPS 392
#pragma unroll
        for (int qq = 0; qq < 4; qq++) {
            __syncthreads();
            int lrow = quad << 2;
#pragma unroll
            for (int cs = 0; cs < 4; cs++) {
                int col = (w << 6) + cs * 16 + l15;
#pragma unroll
                for (int reg = 0; reg < 4; reg++)
                    sh[(lrow + reg) * EPS + col] = f2bf(acc[qq][cs][reg] + bias[cs]);
            }
            __syncthreads();
#pragma unroll
            for (int i = 0; i < 2; i++) {
                int c = tid + i * 384;
                int row = c / 48;
                int col = (c % 48) * 8;
                int grow = row0 + qq * 16 + row;
                if (grow < N) {
                    uint4 val = *(const uint4*)&sh[row * EPS + col];
                    *(uint4*)&qkv[(size_t)grow * QKVD + col] = val;
                }
            }
        }
#undef EPS
    }
#undef PF
#undef PFC
#undef WRCH
}

// ---------------------------------------------------------------------------
// efine: one block per coarse bucket, 128 regions (r10-proven).
// ---------------------------------------------------------------------------
__global__ __launch_bounds__(256) void efine(
    const uint_t* __restrict__ regions, const int* __restrict__ aux,
    int* __restrict__ P, int* __restrict__ sorted_src,
    int N, int NBC, int CH)
{
    __shared__ int rl[128], ro[128], doff[128];
    __shared__ int cnt[128], scn2[128];
    __shared__ uint_t stage[4096];
    __shared__ int    sst[4096];
    __shared__ int s_part[2];
    const int tid = threadIdx.x;
    const int b   = blockIdx.x;

    if (tid < 128) {
        int r0 = aux[b * NSORTB + tid];
        int r1 = aux[(b + 1) * NSORTB + tid];   // b=NBC-1 reads sentinel row
        ro[tid] = r0;
        rl[tid] = r1 - r0;
        doff[tid] = r1 - r0;
        int bsum = r0;
#pragma unroll
        for (int off = 1; off < 64; off <<= 1)
            bsum += __shfl_xor(bsum, off);
        if ((tid & 63) == 0) s_part[tid >> 6] = bsum;
    }
    __syncthreads();
    for (int off = 1; off < 128; off <<= 1) {
        int v = (tid >= off && tid < 128) ? doff[tid - off] : 0;
        __syncthreads();
        if (tid < 128) doff[tid] += v;
        __syncthreads();
    }
    const int m = doff[127];
    const int base = s_part[0] + s_part[1];

    {
        int r = tid >> 1, k = tid & 1;
        int dst0 = doff[r] - rl[r];
        int src0 = ro[r];
        int len  = rl[r];
        for (int i = k; i < len; i += 2)
            stage[dst0 + i] = regions[(size_t)r * CH + src0 + i];
    }
    __syncthreads();

    if (tid < 128) cnt[tid] = 0;
    __syncthreads();
    for (int i = tid; i < m; i += 256)
        atomicAdd(&cnt[stage[i] >> 20], 1);
    __syncthreads();
    if (tid < 128) scn2[tid] = cnt[tid];
    __syncthreads();
    for (int off = 1; off < 128; off <<= 1) {
        int v = (tid >= off && tid < 128) ? scn2[tid - off] : 0;
        __syncthreads();
        if (tid < 128) scn2[tid] += v;
        __syncthreads();
    }
    if (tid < 128) {
        int excl = scn2[tid] - cnt[tid];
        int n = b * 128 + tid;
        if (n < N) P[n] = base + excl;
        cnt[tid] = excl;
    }
    __syncthreads();
    for (int i = tid; i < m; i += 256) {
        uint_t r = stage[i];
        int pos = atomicAdd(&cnt[r >> 20], 1);
        sst[pos] = (int)(r & 0xFFFFFu);
    }
    __syncthreads();
    for (int i = tid; i < m; i += 256)
        sorted_src[base + i] = sst[i];
}

// ---------------------------------------------------------------------------
// Segmented attention reduce + fused normalize (unchanged, proven).
// ---------------------------------------------------------------------------
__global__ __launch_bounds__(256) void segment_attn(
    const ushort_t* __restrict__ qkv,
    const int* __restrict__ P, const int* __restrict__ sorted_src,
    float* __restrict__ out, int N, int E)
{
    int n = (blockIdx.x * 256 + threadIdx.x) >> 4;
    int g = threadIdx.x & 15;
    if (n >= N) return;
    int start = P[n];
    int end   = (n + 1 < N) ? P[n + 1] : E;
    int deg   = end - start;

    const uint_t* qrow = (const uint_t*)(qkv + (size_t)n * QKVD);
    uint4 qu = *(const uint4*)(qrow + g * 4);
    float q0 = bf2f((ushort_t)(qu.x & 0xFFFF)), q1 = bf2f((ushort_t)(qu.x >> 16));
    float q2 = bf2f((ushort_t)(qu.y & 0xFFFF)), q3 = bf2f((ushort_t)(qu.y >> 16));
    float q4 = bf2f((ushort_t)(qu.z & 0xFFFF)), q5 = bf2f((ushort_t)(qu.z >> 16));
    float q6 = bf2f((ushort_t)(qu.w & 0xFFFF)), q7 = bf2f((ushort_t)(qu.w >> 16));

    float a0 = 0.f, a1 = 0.f, a2 = 0.f, a3 = 0.f;
    float a4 = 0.f, a5 = 0.f, a6 = 0.f, a7 = 0.f, z = 0.f;

    int myidx = (g < deg) ? sorted_src[start + g] : 0;
    int wbase = (threadIdx.x & 63) & 48;

#define PROC(ku, vu)                                                       \
    {                                                                      \
        float p = bf2f((ushort_t)((ku).x & 0xFFFF)) * q0                   \
                + bf2f((ushort_t)((ku).x >> 16))    * q1                   \
                + bf2f((ushort_t)((ku).y & 0xFFFF)) * q2                   \
                + bf2f((ushort_t)((ku).y >> 16))    * q3                   \
                + bf2f((ushort_t)((ku).z & 0xFFFF)) * q4                   \
                + bf2f((ushort_t)((ku).z >> 16))    * q5                   \
                + bf2f((ushort_t)((ku).w & 0xFFFF)) * q6                   \
                + bf2f((ushort_t)((ku).w >> 16))    * q7;                  \
        p += __shfl_xor(p, 1);                                             \
        p = fminf(fmaxf(p * 0.25f, -5.f), 5.f);                            \
        float s = __expf(p);                                               \
        a0 += bf2f((ushort_t)((vu).x & 0xFFFF)) * s;                       \
        a1 += bf2f((ushort_t)((vu).x >> 16))    * s;                       \
        a2 += bf2f((ushort_t)((vu).y & 0xFFFF)) * s;                       \
        a3 += bf2f((ushort_t)((vu).y >> 16))    * s;                       \
        a4 += bf2f((ushort_t)((vu).z & 0xFFFF)) * s;                       \
        a5 += bf2f((ushort_t)((vu).z >> 16))    * s;                       \
        a6 += bf2f((ushort_t)((vu).w & 0xFFFF)) * s;                       \
        a7 += bf2f((ushort_t)((vu).w >> 16))    * s;                       \
        z += s;                                                            \
    }

    int cnt = (deg < 16) ? deg : 16;
    int t = 0;
    for (; t + 4 <= cnt; t += 4) {
        int s0 = __shfl(myidx, wbase + t);
        int s1 = __shfl(myidx, wbase + t + 1);
        int s2 = __shfl(myidx, wbase + t + 2);
        int s3 = __shfl(myidx, wbase + t + 3);
        const uint_t* kv0 = (const uint_t*)(qkv + (size_t)s0 * QKVD + 128);
        const uint_t* kv1 = (const uint_t*)(qkv + (size_t)s1 * QKVD + 128);
        const uint_t* kv2 = (const uint_t*)(qkv + (size_t)s2 * QKVD + 128);
        const uint_t* kv3 = (const uint_t*)(qkv + (size_t)s3 * QKVD + 128);
        uint4 ku0 = *(const uint4*)(kv0 + g * 4);
        uint4 ku1 = *(const uint4*)(kv1 + g * 4);
        uint4 ku2 = *(const uint4*)(kv2 + g * 4);
        uint4 ku3 = *(const uint4*)(kv3 + g * 4);
        uint4 vu0 = *(const uint4*)(kv0 + 64 + g * 4);
        uint4 vu1 = *(const uint4*)(kv1 + 64 + g * 4);
        uint4 vu2 = *(const uint4*)(kv2 + 64 + g * 4);
        uint4 vu3 = *(const uint4*)(kv3 + 64 + g * 4);
        PROC(ku0, vu0); PROC(ku1, vu1); PROC(ku2, vu2); PROC(ku3, vu3);
    }
    for (; t + 2 <= cnt; t += 2) {
        int s0 = __shfl(myidx, wbase + t);
        int s1 = __shfl(myidx, wbase + t + 1);
        const uint_t* kv0 = (const uint_t*)(qkv + (size_t)s0 * QKVD + 128);
        const uint_t* kv1 = (const uint_t*)(qkv + (size_t)s1 * QKVD + 128);
        uint4 ku0 = *(const uint4*)(kv0 + g * 4);
        uint4 ku1 = *(const uint4*)(kv1 + g * 4);
        uint4 vu0 = *(const uint4*)(kv0 + 64 + g * 4);
        uint4 vu1 = *(const uint4*)(kv1 + 64 + g * 4);
        PROC(ku0, vu0); PROC(ku1, vu1);
    }
    if (t < cnt) {
        int s0 = __shfl(myidx, wbase + t);
        const uint_t* kv0 = (const uint_t*)(qkv + (size_t)s0 * QKVD + 128);
        uint4 ku0 = *(const uint4*)(kv0 + g * 4);
        uint4 vu0 = *(const uint4*)(kv0 + 64 + g * 4);
        PROC(ku0, vu0);
    }
    for (int j = start + 16; j + 2 <= end; j += 2) {
        int s0 = sorted_src[j];
        int s1 = sorted_src[j + 1];
        const uint_t* kv0 = (const uint_t*)(qkv + (size_t)s0 * QKVD + 128);
        const uint_t* kv1 = (const uint_t*)(qkv + (size_t)s1 * QKVD + 128);
        uint4 ku0 = *(const uint4*)(kv0 + g * 4);
        uint4 ku1 = *(const uint4*)(kv1 + g * 4);
        uint4 vu0 = *(const uint4*)(kv0 + 64 + g * 4);
        uint4 vu1 = *(const uint4*)(kv1 + 64 + g * 4);
        PROC(ku0, vu0); PROC(ku1, vu1);
    }
    if (deg > 16 && ((deg - 16) & 1)) {
        int s0 = sorted_src[end - 1];
        const uint_t* kv0 = (const uint_t*)(qkv + (size_t)s0 * QKVD + 128);
        uint4 ku0 = *(const uint4*)(kv0 + g * 4);
        uint4 vu0 = *(const uint4*)(kv0 + 64 + g * 4);
        PROC(ku0, vu0);
    }
#undef PROC

    float inv = 1.f / (z + 1e-6f);
    f32x4 o0 = {a0 * inv, a1 * inv, a2 * inv, a3 * inv};
    f32x4 o1 = {a4 * inv, a5 * inv, a6 * inv, a7 * inv};
    float* ob = out + (size_t)n * OUTD + g * 8;
    __builtin_nontemporal_store(o0, (f32x4*)ob);
    __builtin_nontemporal_store(o1, (f32x4*)(ob + 4));
}

extern "C" void kernel_launch(void* const* d_in, const int* in_sizes, int n_in,
                              void* d_out, int out_size, void* d_ws, size_t ws_size,
                              hipStream_t stream) {
    const float* x  = (const float*)d_in[0];
    const int*   ei = (const int*)d_in[1];
    const float* Wq = (const float*)d_in[4];
    const float* bq = (const float*)d_in[5];
    const float* Wk = (const float*)d_in[6];
    const float* bk = (const float*)d_in[7];
    const float* Wv = (const float*)d_in[8];
    const float* bv = (const float*)d_in[9];
    float* out = (float*)d_out;

    const int N = in_sizes[0] / IN_DIM;     // 100000
    const int E = in_sizes[1] / 2;          // 800000
    const int NBC = (N + 127) >> 7;         // 782 coarse buckets
    const int CH  = (E + NSORTB - 1) / NSORTB;   // 6250 edges/region

    char* wsb = (char*)d_ws;
    ushort_t* qkv = (ushort_t*)wsb;                          // N*384 bf16
    ushort_t* Wt  = qkv + (size_t)N * QKVD;                  // 384*128 bf16
    int* aux = (int*)(Wt + 384 * 128);                       // (NBC+1)*128 ints
    uint_t* regions = (uint_t*)(aux + (NBC + 1) * NSORTB);   // E uints
    int* sorted = (int*)(regions + (size_t)NSORTB * CH);     // E ints
    int* P = sorted + E;                                     // N ints

    const int ntiles = (N + 63) / 64;       // 1563

    prep_w<<<48, 256, 0, stream>>>(Wq, Wk, Wv, Wt);
    fat_gemm_sort<<<GRID, 384, 0, stream>>>(
        x, Wt, bq, bk, bv, qkv, ei, aux, regions, N, E, ntiles, NBC, CH);
    efine<<<NBC, 256, 0, stream>>>(regions, aux, P, sorted, N, NBC, CH);
    segment_attn<<<((size_t)N * 16 + 255) / 256, 256, 0, stream>>>(
        qkv, P, sorted, out, N, E);
}

// Round 14
// 261.275 us; speedup vs baseline: 1.0083x; 1.0083x over previous
//
#include <hip/hip_runtime.h>

#define IN_DIM   128
#define NH       8
#define HD       16
#define OUTD     128   // NH*HD
#define QKVD     384   // Q|K|V per node, bf16
#define SH       7     // coarse bucket = 128 nodes
#define NSORTB   128   // sort blocks (private regions)
#define GRID     1024  // 4 blocks/CU on 256 CUs, all co-resident

typedef unsigned short ushort_t;
typedef unsigned int   uint_t;
typedef __bf16 bf16x8 __attribute__((ext_vector_type(8)));
typedef float  f32x4  __attribute__((ext_vector_type(4)));

#define AGT __HIP_MEMORY_SCOPE_AGENT

__device__ __forceinline__ float bf2f(ushort_t u) {
    return __uint_as_float(((uint_t)u) << 16);
}
__device__ __forceinline__ ushort_t f2bf(float f) {
    uint_t u = __float_as_uint(f);
    u += 0x7FFFu + ((u >> 16) & 1u);      // RNE
    return (ushort_t)(u >> 16);
}

// ---------------------------------------------------------------------------
// fat_all: 1024 blocks x 384 thr, 4 blocks/CU (LDS 35.4KB, VGPR ~84).
//  - blocks [0,128): coarse counting sort of a 6250-edge chunk (r10-proven),
//    then counter-sync among the 128 sort blocks, then WORK-STEAL the 782
//    efine buckets (fine-sort -> P, sorted_src). All hidden under the GEMM.
//  - blocks [128,1024): persistent bf16 MFMA GEMM over 64-row tiles -> qkv
//    (r10-proven loop; B fragments converted in-register from fp32 W, so the
//    prep_w kernel is deleted).
// Safety: grid == exact residency capacity (1024 = 256 CU x 4 blocks), so
// the sort blocks' spin cannot deadlock; only sort blocks spin, and all 128
// complete their sort phase without waiting on anyone.
// ---------------------------------------------------------------------------
__global__ __launch_bounds__(384, 3) void fat_all(
    const float* __restrict__ x,
    const float* __restrict__ Wq, const float* __restrict__ bq,
    const float* __restrict__ Wk, const float* __restrict__ bk,
    const float* __restrict__ Wv, const float* __restrict__ bv,
    ushort_t* __restrict__ qkv,
    const int* __restrict__ ei, int* __restrict__ aux,
    uint_t* __restrict__ regions,
    int* __restrict__ P, int* __restrict__ sorted_src, int* ctr,
    int N, int E, int ntiles, int NBC, int CH)
{
    __shared__ __align__(16) char smem[35344];
    const int tid = threadIdx.x;

    if (blockIdx.x < NSORTB) {
        // ================= phase S: coarse sort (r10-proven) ===============
        {
            uint_t* recs = (uint_t*)smem;                 // 6250*4 = 25000 B
            int* hist    = (int*)(smem + 25000);          // 1024*4
            int* scn     = (int*)(smem + 29096);          // 1024*4
            const int blk = blockIdx.x;
            const int e0g = blk * CH;
            const int e1g = min(E, e0g + CH);
            const int m   = e1g - e0g;

            for (int i = tid; i < 1024; i += 384) hist[i] = 0;
            __syncthreads();
            for (int e = e0g + tid; e < e1g; e += 384)
                atomicAdd(&hist[ei[E + e] >> SH], 1);
            __syncthreads();
            if (tid < 64) {       // wave 0: exclusive scan of 1024 bins
                int base16 = tid * 16;
                int loc[16]; int s = 0;
#pragma unroll
                for (int i = 0; i < 16; i++) { loc[i] = s; s += hist[base16 + i]; }
                int incl = s;
                for (int off = 1; off < 64; off <<= 1) {
                    int t = __shfl_up(incl, off);
                    if (tid >= off) incl += t;
                }
                int cexcl = incl - s;
#pragma unroll
                for (int i = 0; i < 16; i++) scn[base16 + i] = cexcl + loc[i];
            }
            __syncthreads();
            for (int b = tid; b < NBC; b += 384) aux[b * NSORTB + blk] = scn[b];
            if (tid == 0) aux[NBC * NSORTB + blk] = m;   // sentinel row
            __syncthreads();
            for (int e = e0g + tid; e < e1g; e += 384) {
                int d = ei[E + e];
                int src = ei[e];
                int slot = atomicAdd(&scn[d >> SH], 1);
                recs[slot] = (uint_t)src | ((uint_t)(d & 127) << 20);
            }
            __syncthreads();
            for (int s = tid; s < m; s += 384)
                regions[(size_t)blk * CH + s] = recs[s];
        }
        __syncthreads();
        if (tid == 0) {
            __hip_atomic_fetch_add(&ctr[0], 1, __ATOMIC_RELEASE, AGT);
            while (__hip_atomic_load(&ctr[0], __ATOMIC_RELAXED, AGT) < NSORTB)
                __builtin_amdgcn_s_sleep(8);
            (void)__hip_atomic_load(&ctr[0], __ATOMIC_ACQUIRE, AGT);
        }
        __syncthreads();

        // ================= phase F: efine work-steal =======================
        uint_t* stage = (uint_t*)smem;             // 16384 B
        int* sst   = (int*)(smem + 16384);         // 16384 B
        int* rl    = (int*)(smem + 32768);         // 128 ints
        int* ro    = (int*)(smem + 33280);
        int* doff  = (int*)(smem + 33792);
        int* cnt   = (int*)(smem + 34304);
        int* scn2  = (int*)(smem + 34816);
        int* sparts = (int*)(smem + 35328);        // 2 ints
        int* s_word = (int*)(smem + 35336);

        for (;;) {
            __syncthreads();
            if (tid == 0)
                *s_word = __hip_atomic_fetch_add(&ctr[1], 1, __ATOMIC_RELAXED, AGT);
            __syncthreads();
            const int b = *s_word;
            if (b >= NBC) break;

            if (tid < 128) {
                int r0 = aux[b * NSORTB + tid];
                int r1 = aux[(b + 1) * NSORTB + tid];  // b=NBC-1 -> sentinel
                ro[tid] = r0; rl[tid] = r1 - r0; doff[tid] = r1 - r0;
                int bsum = r0;
#pragma unroll
                for (int off = 1; off < 64; off <<= 1)
                    bsum += __shfl_xor(bsum, off);
                if ((tid & 63) == 0) sparts[tid >> 6] = bsum;
            }
            __syncthreads();
            for (int off = 1; off < 128; off <<= 1) {
                int v = (tid >= off && tid < 128) ? doff[tid - off] : 0;
                __syncthreads();
                if (tid < 128) doff[tid] += v;
                __syncthreads();
            }
            const int m2  = doff[127];
            const int base = sparts[0] + sparts[1];

            {   // gather runs: 2 lanes per region
                int r = tid >> 1, k = tid & 1;
                if (r < 128) {
                    int dst0 = doff[r] - rl[r];
                    int src0 = ro[r];
                    int len  = rl[r];
                    for (int i = k; i < len; i += 2)
                        stage[dst0 + i] = regions[(size_t)r * CH + src0 + i];
                }
            }
            __syncthreads();

            if (tid < 128) cnt[tid] = 0;
            __syncthreads();
            for (int i = tid; i < m2; i += 384)
                atomicAdd(&cnt[stage[i] >> 20], 1);
            __syncthreads();
            if (tid < 128) scn2[tid] = cnt[tid];
            __syncthreads();
            for (int off = 1; off < 128; off <<= 1) {
                int v = (tid >= off && tid < 128) ? scn2[tid - off] : 0;
                __syncthreads();
                if (tid < 128) scn2[tid] += v;
                __syncthreads();
            }
            if (tid < 128) {
                int excl = scn2[tid] - cnt[tid];
                int n = b * 128 + tid;
                if (n < N) P[n] = base + excl;
                cnt[tid] = excl;
            }
            __syncthreads();
            for (int i = tid; i < m2; i += 384) {
                uint_t r = stage[i];
                int pos = atomicAdd(&cnt[r >> 20], 1);
                sst[pos] = (int)(r & 0xFFFFFu);
            }
            __syncthreads();
            for (int i = tid; i < m2; i += 384)
                sorted_src[base + i] = sst[i];
        }
        return;
    }

    // ================= gemm path (r10-proven loop) =========================
    ushort_t* sh = (ushort_t*)smem;   // uses 16640 B of the 35344

    const int w    = tid >> 6;        // wave 0..5
    const int quad = (tid >> 4) & 3;
    const int l15  = tid & 15;
    const int mat  = w >> 1;          // 0=Q,1=K,2=V
    const float* Wsel = (mat == 0) ? Wq : (mat == 1) ? Wk : Wv;
    const float* Bp   = (mat == 0) ? bq : (mat == 1) ? bk : bv;

    // B fragments straight from fp32 W (192 KB total, L2-hot) — no prep_w.
    bf16x8 bfr[4][4];
#pragma unroll
    for (int kt = 0; kt < 4; kt++)
#pragma unroll
        for (int cs = 0; cs < 4; cs++) {
            int c = ((w & 1) << 6) + cs * 16 + l15;
            union { ushort_t h[8]; bf16x8 v; } u;
#pragma unroll
            for (int j = 0; j < 8; j++)
                u.h[j] = f2bf(Wsel[(size_t)(kt * 32 + quad * 8 + j) * 128 + c]);
            bfr[kt][cs] = u.v;
        }
    float bias[4];
#pragma unroll
    for (int cs = 0; cs < 4; cs++)
        bias[cs] = Bp[((w & 1) << 6) + cs * 16 + l15];

    const int gstride = (int)gridDim.x - NSORTB;
    for (int tile = (int)blockIdx.x - NSORTB; tile < ntiles; tile += gstride) {
        const int row0 = tile * 64;
        __syncthreads();   // protect sh from previous iteration's readers

        for (int ch = tid; ch < 1024; ch += 384) {
            int row = ch >> 4;
            int kc  = ch & 15;
            int grow = row0 + row; if (grow > N - 1) grow = N - 1;
            const float* xp = x + (size_t)grow * IN_DIM + kc * 8;
            float4 f0 = *(const float4*)xp;
            float4 f1 = *(const float4*)(xp + 4);
            union { ushort_t h[8]; uint4 u; } tt;
            tt.h[0] = f2bf(f0.x); tt.h[1] = f2bf(f0.y);
            tt.h[2] = f2bf(f0.z); tt.h[3] = f2bf(f0.w);
            tt.h[4] = f2bf(f1.x); tt.h[5] = f2bf(f1.y);
            tt.h[6] = f2bf(f1.z); tt.h[7] = f2bf(f1.w);
            *(uint4*)&sh[(kc * 65 + row) * 8] = tt.u;
        }
        __syncthreads();

        f32x4 acc[4][4];
#pragma unroll
        for (int r = 0; r < 4; r++)
#pragma unroll
            for (int cs = 0; cs < 4; cs++) acc[r][cs] = (f32x4){0.f, 0.f, 0.f, 0.f};

#pragma unroll
        for (int kt = 0; kt < 4; kt++) {
            int kc = kt * 4 + quad;
            bf16x8 af[4];
#pragma unroll
            for (int r = 0; r < 4; r++)
                af[r] = *(const bf16x8*)&sh[(kc * 65 + r * 16 + l15) * 8];
#pragma unroll
            for (int r = 0; r < 4; r++)
#pragma unroll
                for (int cs = 0; cs < 4; cs++)
                    acc[r][cs] = __builtin_amdgcn_mfma_f32_16x16x32_bf16(
                        af[r], bfr[kt][cs], acc[r][cs], 0, 0, 0);
        }

#define EPS 392
#pragma unroll
        for (int qq = 0; qq < 4; qq++) {
            __syncthreads();
            int lrow = quad << 2;
#pragma unroll
            for (int cs = 0; cs < 4; cs++) {
                int col = (w << 6) + cs * 16 + l15;
#pragma unroll
                for (int reg = 0; reg < 4; reg++)
                    sh[(lrow + reg) * EPS + col] = f2bf(acc[qq][cs][reg] + bias[cs]);
            }
            __syncthreads();
#pragma unroll
            for (int i = 0; i < 2; i++) {
                int c = tid + i * 384;
                int row = c / 48;
                int col = (c % 48) * 8;
                int grow = row0 + qq * 16 + row;
                if (grow < N) {
                    uint4 val = *(const uint4*)&sh[row * EPS + col];
                    *(uint4*)&qkv[(size_t)grow * QKVD + col] = val;
                }
            }
        }
#undef EPS
    }
}

// ---------------------------------------------------------------------------
// Segmented attention reduce + fused normalize (unchanged, proven).
// ---------------------------------------------------------------------------
__global__ __launch_bounds__(256) void segment_attn(
    const ushort_t* __restrict__ qkv,
    const int* __restrict__ P, const int* __restrict__ sorted_src,
    float* __restrict__ out, int N, int E)
{
    int n = (blockIdx.x * 256 + threadIdx.x) >> 4;
    int g = threadIdx.x & 15;
    if (n >= N) return;
    int start = P[n];
    int end   = (n + 1 < N) ? P[n + 1] : E;
    int deg   = end - start;

    const uint_t* qrow = (const uint_t*)(qkv + (size_t)n * QKVD);
    uint4 qu = *(const uint4*)(qrow + g * 4);
    float q0 = bf2f((ushort_t)(qu.x & 0xFFFF)), q1 = bf2f((ushort_t)(qu.x >> 16));
    float q2 = bf2f((ushort_t)(qu.y & 0xFFFF)), q3 = bf2f((ushort_t)(qu.y >> 16));
    float q4 = bf2f((ushort_t)(qu.z & 0xFFFF)), q5 = bf2f((ushort_t)(qu.z >> 16));
    float q6 = bf2f((ushort_t)(qu.w & 0xFFFF)), q7 = bf2f((ushort_t)(qu.w >> 16));

    float a0 = 0.f, a1 = 0.f, a2 = 0.f, a3 = 0.f;
    float a4 = 0.f, a5 = 0.f, a6 = 0.f, a7 = 0.f, z = 0.f;

    int myidx = (g < deg) ? sorted_src[start + g] : 0;
    int wbase = (threadIdx.x & 63) & 48;

#define PROC(ku, vu)                                                       \
    {                                                                      \
        float p = bf2f((ushort_t)((ku).x & 0xFFFF)) * q0                   \
                + bf2f((ushort_t)((ku).x >> 16))    * q1                   \
                + bf2f((ushort_t)((ku).y & 0xFFFF)) * q2                   \
                + bf2f((ushort_t)((ku).y >> 16))    * q3                   \
                + bf2f((ushort_t)((ku).z & 0xFFFF)) * q4                   \
                + bf2f((ushort_t)((ku).z >> 16))    * q5                   \
                + bf2f((ushort_t)((ku).w & 0xFFFF)) * q6                   \
                + bf2f((ushort_t)((ku).w >> 16))    * q7;                  \
        p += __shfl_xor(p, 1);                                             \
        p = fminf(fmaxf(p * 0.25f, -5.f), 5.f);                            \
        float s = __expf(p);                                               \
        a0 += bf2f((ushort_t)((vu).x & 0xFFFF)) * s;                       \
        a1 += bf2f((ushort_t)((vu).x >> 16))    * s;                       \
        a2 += bf2f((ushort_t)((vu).y & 0xFFFF)) * s;                       \
        a3 += bf2f((ushort_t)((vu).y >> 16))    * s;                       \
        a4 += bf2f((ushort_t)((vu).z & 0xFFFF)) * s;                       \
        a5 += bf2f((ushort_t)((vu).z >> 16))    * s;                       \
        a6 += bf2f((ushort_t)((vu).w & 0xFFFF)) * s;                       \
        a7 += bf2f((ushort_t)((vu).w >> 16))    * s;                       \
        z += s;                                                            \
    }

    int cnt = (deg < 16) ? deg : 16;
    int t = 0;
    for (; t + 4 <= cnt; t += 4) {
        int s0 = __shfl(myidx, wbase + t);
        int s1 = __shfl(myidx, wbase + t + 1);
        int s2 = __shfl(myidx, wbase + t + 2);
        int s3 = __shfl(myidx, wbase + t + 3);
        const uint_t* kv0 = (const uint_t*)(qkv + (size_t)s0 * QKVD + 128);
        const uint_t* kv1 = (const uint_t*)(qkv + (size_t)s1 * QKVD + 128);
        const uint_t* kv2 = (const uint_t*)(qkv + (size_t)s2 * QKVD + 128);
        const uint_t* kv3 = (const uint_t*)(qkv + (size_t)s3 * QKVD + 128);
        uint4 ku0 = *(const uint4*)(kv0 + g * 4);
        uint4 ku1 = *(const uint4*)(kv1 + g * 4);
        uint4 ku2 = *(const uint4*)(kv2 + g * 4);
        uint4 ku3 = *(const uint4*)(kv3 + g * 4);
        uint4 vu0 = *(const uint4*)(kv0 + 64 + g * 4);
        uint4 vu1 = *(const uint4*)(kv1 + 64 + g * 4);
        uint4 vu2 = *(const uint4*)(kv2 + 64 + g * 4);
        uint4 vu3 = *(const uint4*)(kv3 + 64 + g * 4);
        PROC(ku0, vu0); PROC(ku1, vu1); PROC(ku2, vu2); PROC(ku3, vu3);
    }
    for (; t + 2 <= cnt; t += 2) {
        int s0 = __shfl(myidx, wbase + t);
        int s1 = __shfl(myidx, wbase + t + 1);
        const uint_t* kv0 = (const uint_t*)(qkv + (size_t)s0 * QKVD + 128);
        const uint_t* kv1 = (const uint_t*)(qkv + (size_t)s1 * QKVD + 128);
        uint4 ku0 = *(const uint4*)(kv0 + g * 4);
        uint4 ku1 = *(const uint4*)(kv1 + g * 4);
        uint4 vu0 = *(const uint4*)(kv0 + 64 + g * 4);
        uint4 vu1 = *(const uint4*)(kv1 + 64 + g * 4);
        PROC(ku0, vu0); PROC(ku1, vu1);
    }
    if (t < cnt) {
        int s0 = __shfl(myidx, wbase + t);
        const uint_t* kv0 = (const uint_t*)(qkv + (size_t)s0 * QKVD + 128);
        uint4 ku0 = *(const uint4*)(kv0 + g * 4);
        uint4 vu0 = *(const uint4*)(kv0 + 64 + g * 4);
        PROC(ku0, vu0);
    }
    for (int j = start + 16; j + 2 <= end; j += 2) {
        int s0 = sorted_src[j];
        int s1 = sorted_src[j + 1];
        const uint_t* kv0 = (const uint_t*)(qkv + (size_t)s0 * QKVD + 128);
        const uint_t* kv1 = (const uint_t*)(qkv + (size_t)s1 * QKVD + 128);
        uint4 ku0 = *(const uint4*)(kv0 + g * 4);
        uint4 ku1 = *(const uint4*)(kv1 + g * 4);
        uint4 vu0 = *(const uint4*)(kv0 + 64 + g * 4);
        uint4 vu1 = *(const uint4*)(kv1 + 64 + g * 4);
        PROC(ku0, vu0); PROC(ku1, vu1);
    }
    if (deg > 16 && ((deg - 16) & 1)) {
        int s0 = sorted_src[end - 1];
        const uint_t* kv0 = (const uint_t*)(qkv + (size_t)s0 * QKVD + 128);
        uint4 ku0 = *(const uint4*)(kv0 + g * 4);
        uint4 vu0 = *(const uint4*)(kv0 + 64 + g * 4);
        PROC(ku0, vu0);
    }
#undef PROC

    float inv = 1.f / (z + 1e-6f);
    f32x4 o0 = {a0 * inv, a1 * inv, a2 * inv, a3 * inv};
    f32x4 o1 = {a4 * inv, a5 * inv, a6 * inv, a7 * inv};
    float* ob = out + (size_t)n * OUTD + g * 8;
    __builtin_nontemporal_store(o0, (f32x4*)ob);
    __builtin_nontemporal_store(o1, (f32x4*)(ob + 4));
}

extern "C" void kernel_launch(void* const* d_in, const int* in_sizes, int n_in,
                              void* d_out, int out_size, void* d_ws, size_t ws_size,
                              hipStream_t stream) {
    const float* x  = (const float*)d_in[0];
    const int*   ei = (const int*)d_in[1];
    const float* Wq = (const float*)d_in[4];
    const float* bq = (const float*)d_in[5];
    const float* Wk = (const float*)d_in[6];
    const float* bk = (const float*)d_in[7];
    const float* Wv = (const float*)d_in[8];
    const float* bv = (const float*)d_in[9];
    float* out = (float*)d_out;

    const int N = in_sizes[0] / IN_DIM;     // 100000
    const int E = in_sizes[1] / 2;          // 800000
    const int NBC = (N + 127) >> 7;         // 782 coarse buckets
    const int CH  = (E + NSORTB - 1) / NSORTB;   // 6250 edges/region

    char* wsb = (char*)d_ws;
    ushort_t* qkv = (ushort_t*)wsb;                          // N*384 bf16
    int* aux = (int*)(qkv + (size_t)N * QKVD);               // (NBC+1)*128 ints
    uint_t* regions = (uint_t*)(aux + (NBC + 1) * NSORTB);   // E uints
    int* sorted = (int*)(regions + (size_t)NSORTB * CH);     // E ints
    int* P = sorted + E;                                     // N ints
    int* ctr = P + N;                                        // 2 ints

    const int ntiles = (N + 63) / 64;       // 1563

    hipMemsetAsync(ctr, 0, 8, stream);
    fat_all<<<GRID, 384, 0, stream>>>(
        x, Wq, bq, Wk, bk, Wv, bv, qkv, ei, aux, regions,
        P, sorted, ctr, N, E, ntiles, NBC, CH);
    segment_attn<<<((size_t)N * 16 + 255) / 256, 256, 0, stream>>>(
        qkv, P, sorted, out, N, E);
}

// Round 15
// 240.394 us; speedup vs baseline: 1.0959x; 1.0869x over previous
//
#include <hip/hip_runtime.h>

#define IN_DIM   128
#define NH       8
#define HD       16
#define OUTD     128   // NH*HD
#define QKVD     384   // Q|K|V per node, bf16
#define SH       7     // coarse bucket = 128 nodes
#define NSORTB   128   // sort blocks (private regions) -> 33.2KB LDS
#define GRID     1024

typedef unsigned short ushort_t;
typedef unsigned int   uint_t;
typedef __bf16 bf16x8 __attribute__((ext_vector_type(8)));
typedef float  f32x4  __attribute__((ext_vector_type(4)));

__device__ __forceinline__ float bf2f(ushort_t u) {
    return __uint_as_float(((uint_t)u) << 16);
}
__device__ __forceinline__ ushort_t f2bf(float f) {
    uint_t u = __float_as_uint(f);
    u += 0x7FFFu + ((u >> 16) & 1u);      // RNE
    return (ushort_t)(u >> 16);
}

// ---------------------------------------------------------------------------
// prep_w: W[k][c] fp32 (3 mats) -> Wt[col][k] bf16, col in [0,384).
// ---------------------------------------------------------------------------
__global__ __launch_bounds__(256) void prep_w(
    const float* __restrict__ Wq, const float* __restrict__ Wk,
    const float* __restrict__ Wv, ushort_t* __restrict__ Wt)
{
    __shared__ float ld[32][33];
    int mat  = blockIdx.x >> 4;
    int tile = blockIdx.x & 15;
    int k0 = (tile >> 2) * 32, c0 = (tile & 3) * 32;
    const float* W = (mat == 0) ? Wq : (mat == 1) ? Wk : Wv;
    int t = threadIdx.x;
    {
        int k = t >> 3, c4 = (t & 7) * 4;
        float4 f = *(const float4*)&W[(size_t)(k0 + k) * 128 + c0 + c4];
        ld[k][c4 + 0] = f.x; ld[k][c4 + 1] = f.y;
        ld[k][c4 + 2] = f.z; ld[k][c4 + 3] = f.w;
    }
    __syncthreads();
    {
        int c = t >> 3, kg = (t & 7) * 4;
        union { ushort_t h[4]; uint2 u; } o;
        o.h[0] = f2bf(ld[kg + 0][c]); o.h[1] = f2bf(ld[kg + 1][c]);
        o.h[2] = f2bf(ld[kg + 2][c]); o.h[3] = f2bf(ld[kg + 3][c]);
        *(uint2*)&Wt[((size_t)(mat * 128 + c0 + c)) * 128 + k0 + kg] = o.u;
    }
}

// ---------------------------------------------------------------------------
// FAT kernel: 1024 blocks x 384 thr, 4 blocks/CU (LDS 33.2KB).
//  - blocks [0,128): coarse counting sort of 6250-edge chunks.
//  - blocks [128,1024): persistent bf16 MFMA GEMM over 64-row tiles -> qkv.
// (r10-proven configuration — best measured: 240.7 us total.)
// ---------------------------------------------------------------------------
__global__ __launch_bounds__(384, 3) void fat_gemm_sort(
    const float* __restrict__ x, const ushort_t* __restrict__ Wt,
    const float* __restrict__ bq, const float* __restrict__ bk,
    const float* __restrict__ bv, ushort_t* __restrict__ qkv,
    const int* __restrict__ ei, int* __restrict__ aux,
    uint_t* __restrict__ regions,
    int N, int E, int ntiles, int NBC, int CH)
{
    __shared__ __align__(16) char smem[33192];

    if (blockIdx.x < NSORTB) {
        // ================= sort path =================
        uint_t* recs = (uint_t*)smem;                 // 6250 * 4 = 25000 B
        int* hist    = (int*)(smem + 25000);          // 1024 * 4
        int* scn     = (int*)(smem + 29096);          // 1024 * 4
        const int tid = threadIdx.x;
        const int blk = blockIdx.x;
        const int e0g = blk * CH;
        const int e1g = min(E, e0g + CH);
        const int m   = e1g - e0g;

        for (int i = tid; i < 1024; i += 384) hist[i] = 0;
        __syncthreads();
        for (int e = e0g + tid; e < e1g; e += 384)
            atomicAdd(&hist[ei[E + e] >> SH], 1);
        __syncthreads();
        if (tid < 64) {           // wave 0: exclusive scan of 1024 bins
            int base16 = tid * 16;
            int loc[16]; int s = 0;
#pragma unroll
            for (int i = 0; i < 16; i++) { loc[i] = s; s += hist[base16 + i]; }
            int incl = s;
            for (int off = 1; off < 64; off <<= 1) {
                int t = __shfl_up(incl, off);
                if (tid >= off) incl += t;
            }
            int cexcl = incl - s;
#pragma unroll
            for (int i = 0; i < 16; i++) scn[base16 + i] = cexcl + loc[i];
        }
        __syncthreads();
        for (int b = tid; b < NBC; b += 384) aux[b * NSORTB + blk] = scn[b];
        if (tid == 0) aux[NBC * NSORTB + blk] = m;   // sentinel row
        __syncthreads();
        for (int e = e0g + tid; e < e1g; e += 384) {
            int d = ei[E + e];
            int src = ei[e];
            int slot = atomicAdd(&scn[d >> SH], 1);
            recs[slot] = (uint_t)src | ((uint_t)(d & 127) << 20);
        }
        __syncthreads();
        for (int s = tid; s < m; s += 384)
            regions[(size_t)blk * CH + s] = recs[s];
        return;
    }

    // ================= gemm path =================
    ushort_t* sh = (ushort_t*)smem;   // uses 16640 B of the 33192

    const int tid  = threadIdx.x;
    const int w    = tid >> 6;        // wave 0..5
    const int quad = (tid >> 4) & 3;
    const int l15  = tid & 15;
    const int colg = w << 6;          // col base 0..320

    bf16x8 bfr[4][4];
#pragma unroll
    for (int kt = 0; kt < 4; kt++)
#pragma unroll
        for (int cs = 0; cs < 4; cs++) {
            int col = colg + cs * 16 + l15;
            bfr[kt][cs] = *(const bf16x8*)&Wt[(size_t)col * 128 + kt * 32 + quad * 8];
        }

    const int mat = w >> 1;           // 0=Q,1=K,2=V
    const float* Bp = (mat == 0) ? bq : (mat == 1) ? bk : bv;
    float bias[4];
#pragma unroll
    for (int cs = 0; cs < 4; cs++)
        bias[cs] = Bp[((w & 1) << 6) + cs * 16 + l15];

    const int gstride = (int)gridDim.x - NSORTB;
    for (int tile = (int)blockIdx.x - NSORTB; tile < ntiles; tile += gstride) {
        const int row0 = tile * 64;
        __syncthreads();   // protect sh from previous iteration's readers

        for (int ch = tid; ch < 1024; ch += 384) {
            int row = ch >> 4;
            int kc  = ch & 15;
            int grow = row0 + row; if (grow > N - 1) grow = N - 1;
            const float* xp = x + (size_t)grow * IN_DIM + kc * 8;
            float4 f0 = *(const float4*)xp;
            float4 f1 = *(const float4*)(xp + 4);
            union { ushort_t h[8]; uint4 u; } tt;
            tt.h[0] = f2bf(f0.x); tt.h[1] = f2bf(f0.y);
            tt.h[2] = f2bf(f0.z); tt.h[3] = f2bf(f0.w);
            tt.h[4] = f2bf(f1.x); tt.h[5] = f2bf(f1.y);
            tt.h[6] = f2bf(f1.z); tt.h[7] = f2bf(f1.w);
            *(uint4*)&sh[(kc * 65 + row) * 8] = tt.u;
        }
        __syncthreads();

        f32x4 acc[4][4];
#pragma unroll
        for (int r = 0; r < 4; r++)
#pragma unroll
            for (int cs = 0; cs < 4; cs++) acc[r][cs] = (f32x4){0.f, 0.f, 0.f, 0.f};

#pragma unroll
        for (int kt = 0; kt < 4; kt++) {
            int kc = kt * 4 + quad;
            bf16x8 af[4];
#pragma unroll
            for (int r = 0; r < 4; r++)
                af[r] = *(const bf16x8*)&sh[(kc * 65 + r * 16 + l15) * 8];
#pragma unroll
            for (int r = 0; r < 4; r++)
#pragma unroll
                for (int cs = 0; cs < 4; cs++)
                    acc[r][cs] = __builtin_amdgcn_mfma_f32_16x16x32_bf16(
                        af[r], bfr[kt][cs], acc[r][cs], 0, 0, 0);
        }

#define EPS 392
#pragma unroll
        for (int qq = 0; qq < 4; qq++) {
            __syncthreads();
            int lrow = quad << 2;
#pragma unroll
            for (int cs = 0; cs < 4; cs++) {
                int col = (w << 6) + cs * 16 + l15;
#pragma unroll
                for (int reg = 0; reg < 4; reg++)
                    sh[(lrow + reg) * EPS + col] = f2bf(acc[qq][cs][reg] + bias[cs]);
            }
            __syncthreads();
#pragma unroll
            for (int i = 0; i < 2; i++) {
                int c = tid + i * 384;
                int row = c / 48;
                int col = (c % 48) * 8;
                int grow = row0 + qq * 16 + row;
                if (grow < N) {
                    uint4 val = *(const uint4*)&sh[row * EPS + col];
                    *(uint4*)&qkv[(size_t)grow * QKVD + col] = val;
                }
            }
        }
#undef EPS
    }
}

// ---------------------------------------------------------------------------
// efine: one block per coarse bucket, 128 regions. Global CSR base =
// sum_r aux[b*128+r] (two-wave reduction, no scan/lookback).
// ---------------------------------------------------------------------------
__global__ __launch_bounds__(256) void efine(
    const uint_t* __restrict__ regions, const int* __restrict__ aux,
    int* __restrict__ P, int* __restrict__ sorted_src,
    int N, int NBC, int CH)
{
    __shared__ int rl[128], ro[128], doff[128];
    __shared__ int cnt[128], scn2[128];
    __shared__ uint_t stage[4096];
    __shared__ int    sst[4096];
    __shared__ int s_part[2];
    const int tid = threadIdx.x;
    const int b   = blockIdx.x;

    if (tid < 128) {
        int r0 = aux[b * NSORTB + tid];
        int r1 = aux[(b + 1) * NSORTB + tid];   // b=NBC-1 reads sentinel row
        ro[tid] = r0;
        rl[tid] = r1 - r0;
        doff[tid] = r1 - r0;
        int bsum = r0;
#pragma unroll
        for (int off = 1; off < 64; off <<= 1)
            bsum += __shfl_xor(bsum, off);
        if ((tid & 63) == 0) s_part[tid >> 6] = bsum;
    }
    __syncthreads();
    for (int off = 1; off < 128; off <<= 1) {
        int v = (tid >= off && tid < 128) ? doff[tid - off] : 0;
        __syncthreads();
        if (tid < 128) doff[tid] += v;
        __syncthreads();
    }
    const int m = doff[127];
    const int base = s_part[0] + s_part[1];

    {
        int r = tid >> 1, k = tid & 1;
        int dst0 = doff[r] - rl[r];
        int src0 = ro[r];
        int len  = rl[r];
        for (int i = k; i < len; i += 2)
            stage[dst0 + i] = regions[(size_t)r * CH + src0 + i];
    }
    __syncthreads();

    if (tid < 128) cnt[tid] = 0;
    __syncthreads();
    for (int i = tid; i < m; i += 256)
        atomicAdd(&cnt[stage[i] >> 20], 1);
    __syncthreads();
    if (tid < 128) scn2[tid] = cnt[tid];
    __syncthreads();
    for (int off = 1; off < 128; off <<= 1) {
        int v = (tid >= off && tid < 128) ? scn2[tid - off] : 0;
        __syncthreads();
        if (tid < 128) scn2[tid] += v;
        __syncthreads();
    }
    if (tid < 128) {
        int excl = scn2[tid] - cnt[tid];
        int n = b * 128 + tid;
        if (n < N) P[n] = base + excl;
        cnt[tid] = excl;
    }
    __syncthreads();
    for (int i = tid; i < m; i += 256) {
        uint_t r = stage[i];
        int pos = atomicAdd(&cnt[r >> 20], 1);
        sst[pos] = (int)(r & 0xFFFFFu);
    }
    __syncthreads();
    for (int i = tid; i < m; i += 256)
        sorted_src[base + i] = sst[i];
}

// ---------------------------------------------------------------------------
// Segmented attention reduce + fused normalize (proven).
// ---------------------------------------------------------------------------
__global__ __launch_bounds__(256) void segment_attn(
    const ushort_t* __restrict__ qkv,
    const int* __restrict__ P, const int* __restrict__ sorted_src,
    float* __restrict__ out, int N, int E)
{
    int n = (blockIdx.x * 256 + threadIdx.x) >> 4;
    int g = threadIdx.x & 15;
    if (n >= N) return;
    int start = P[n];
    int end   = (n + 1 < N) ? P[n + 1] : E;
    int deg   = end - start;

    const uint_t* qrow = (const uint_t*)(qkv + (size_t)n * QKVD);
    uint4 qu = *(const uint4*)(qrow + g * 4);
    float q0 = bf2f((ushort_t)(qu.x & 0xFFFF)), q1 = bf2f((ushort_t)(qu.x >> 16));
    float q2 = bf2f((ushort_t)(qu.y & 0xFFFF)), q3 = bf2f((ushort_t)(qu.y >> 16));
    float q4 = bf2f((ushort_t)(qu.z & 0xFFFF)), q5 = bf2f((ushort_t)(qu.z >> 16));
    float q6 = bf2f((ushort_t)(qu.w & 0xFFFF)), q7 = bf2f((ushort_t)(qu.w >> 16));

    float a0 = 0.f, a1 = 0.f, a2 = 0.f, a3 = 0.f;
    float a4 = 0.f, a5 = 0.f, a6 = 0.f, a7 = 0.f, z = 0.f;

    int myidx = (g < deg) ? sorted_src[start + g] : 0;
    int wbase = (threadIdx.x & 63) & 48;

#define PROC(ku, vu)                                                       \
    {                                                                      \
        float p = bf2f((ushort_t)((ku).x & 0xFFFF)) * q0                   \
                + bf2f((ushort_t)((ku).x >> 16))    * q1                   \
                + bf2f((ushort_t)((ku).y & 0xFFFF)) * q2                   \
                + bf2f((ushort_t)((ku).y >> 16))    * q3                   \
                + bf2f((ushort_t)((ku).z & 0xFFFF)) * q4                   \
                + bf2f((ushort_t)((ku).z >> 16))    * q5                   \
                + bf2f((ushort_t)((ku).w & 0xFFFF)) * q6                   \
                + bf2f((ushort_t)((ku).w >> 16))    * q7;                  \
        p += __shfl_xor(p, 1);                                             \
        p = fminf(fmaxf(p * 0.25f, -5.f), 5.f);                            \
        float s = __expf(p);                                               \
        a0 += bf2f((ushort_t)((vu).x & 0xFFFF)) * s;                       \
        a1 += bf2f((ushort_t)((vu).x >> 16))    * s;                       \
        a2 += bf2f((ushort_t)((vu).y & 0xFFFF)) * s;                       \
        a3 += bf2f((ushort_t)((vu).y >> 16))    * s;                       \
        a4 += bf2f((ushort_t)((vu).z & 0xFFFF)) * s;                       \
        a5 += bf2f((ushort_t)((vu).z >> 16))    * s;                       \
        a6 += bf2f((ushort_t)((vu).w & 0xFFFF)) * s;                       \
        a7 += bf2f((ushort_t)((vu).w >> 16))    * s;                       \
        z += s;                                                            \
    }

    int cnt = (deg < 16) ? deg : 16;
    int t = 0;
    for (; t + 4 <= cnt; t += 4) {
        int s0 = __shfl(myidx, wbase + t);
        int s1 = __shfl(myidx, wbase + t + 1);
        int s2 = __shfl(myidx, wbase + t + 2);
        int s3 = __shfl(myidx, wbase + t + 3);
        const uint_t* kv0 = (const uint_t*)(qkv + (size_t)s0 * QKVD + 128);
        const uint_t* kv1 = (const uint_t*)(qkv + (size_t)s1 * QKVD + 128);
        const uint_t* kv2 = (const uint_t*)(qkv + (size_t)s2 * QKVD + 128);
        const uint_t* kv3 = (const uint_t*)(qkv + (size_t)s3 * QKVD + 128);
        uint4 ku0 = *(const uint4*)(kv0 + g * 4);
        uint4 ku1 = *(const uint4*)(kv1 + g * 4);
        uint4 ku2 = *(const uint4*)(kv2 + g * 4);
        uint4 ku3 = *(const uint4*)(kv3 + g * 4);
        uint4 vu0 = *(const uint4*)(kv0 + 64 + g * 4);
        uint4 vu1 = *(const uint4*)(kv1 + 64 + g * 4);
        uint4 vu2 = *(const uint4*)(kv2 + 64 + g * 4);
        uint4 vu3 = *(const uint4*)(kv3 + 64 + g * 4);
        PROC(ku0, vu0); PROC(ku1, vu1); PROC(ku2, vu2); PROC(ku3, vu3);
    }
    for (; t + 2 <= cnt; t += 2) {
        int s0 = __shfl(myidx, wbase + t);
        int s1 = __shfl(myidx, wbase + t + 1);
        const uint_t* kv0 = (const uint_t*)(qkv + (size_t)s0 * QKVD + 128);
        const uint_t* kv1 = (const uint_t*)(qkv + (size_t)s1 * QKVD + 128);
        uint4 ku0 = *(const uint4*)(kv0 + g * 4);
        uint4 ku1 = *(const uint4*)(kv1 + g * 4);
        uint4 vu0 = *(const uint4*)(kv0 + 64 + g * 4);
        uint4 vu1 = *(const uint4*)(kv1 + 64 + g * 4);
        PROC(ku0, vu0); PROC(ku1, vu1);
    }
    if (t < cnt) {
        int s0 = __shfl(myidx, wbase + t);
        const uint_t* kv0 = (const uint_t*)(qkv + (size_t)s0 * QKVD + 128);
        uint4 ku0 = *(const uint4*)(kv0 + g * 4);
        uint4 vu0 = *(const uint4*)(kv0 + 64 + g * 4);
        PROC(ku0, vu0);
    }
    for (int j = start + 16; j + 2 <= end; j += 2) {
        int s0 = sorted_src[j];
        int s1 = sorted_src[j + 1];
        const uint_t* kv0 = (const uint_t*)(qkv + (size_t)s0 * QKVD + 128);
        const uint_t* kv1 = (const uint_t*)(qkv + (size_t)s1 * QKVD + 128);
        uint4 ku0 = *(const uint4*)(kv0 + g * 4);
        uint4 ku1 = *(const uint4*)(kv1 + g * 4);
        uint4 vu0 = *(const uint4*)(kv0 + 64 + g * 4);
        uint4 vu1 = *(const uint4*)(kv1 + 64 + g * 4);
        PROC(ku0, vu0); PROC(ku1, vu1);
    }
    if (deg > 16 && ((deg - 16) & 1)) {
        int s0 = sorted_src[end - 1];
        const uint_t* kv0 = (const uint_t*)(qkv + (size_t)s0 * QKVD + 128);
        uint4 ku0 = *(const uint4*)(kv0 + g * 4);
        uint4 vu0 = *(const uint4*)(kv0 + 64 + g * 4);
        PROC(ku0, vu0);
    }
#undef PROC

    float inv = 1.f / (z + 1e-6f);
    f32x4 o0 = {a0 * inv, a1 * inv, a2 * inv, a3 * inv};
    f32x4 o1 = {a4 * inv, a5 * inv, a6 * inv, a7 * inv};
    float* ob = out + (size_t)n * OUTD + g * 8;
    __builtin_nontemporal_store(o0, (f32x4*)ob);
    __builtin_nontemporal_store(o1, (f32x4*)(ob + 4));
}

extern "C" void kernel_launch(void* const* d_in, const int* in_sizes, int n_in,
                              void* d_out, int out_size, void* d_ws, size_t ws_size,
                              hipStream_t stream) {
    const float* x  = (const float*)d_in[0];
    const int*   ei = (const int*)d_in[1];
    const float* Wq = (const float*)d_in[4];
    const float* bq = (const float*)d_in[5];
    const float* Wk = (const float*)d_in[6];
    const float* bk = (const float*)d_in[7];
    const float* Wv = (const float*)d_in[8];
    const float* bv = (const float*)d_in[9];
    float* out = (float*)d_out;

    const int N = in_sizes[0] / IN_DIM;     // 100000
    const int E = in_sizes[1] / 2;          // 800000
    const int NBC = (N + 127) >> 7;         // 782 coarse buckets
    const int CH  = (E + NSORTB - 1) / NSORTB;   // 6250 edges/region

    char* wsb = (char*)d_ws;
    ushort_t* qkv = (ushort_t*)wsb;                          // N*384 bf16
    ushort_t* Wt  = qkv + (size_t)N * QKVD;                  // 384*128 bf16
    int* aux = (int*)(Wt + 384 * 128);                       // (NBC+1)*128 ints
    uint_t* regions = (uint_t*)(aux + (NBC + 1) * NSORTB);   // E uints
    int* sorted = (int*)(regions + (size_t)NSORTB * CH);     // E ints
    int* P = sorted + E;                                     // N ints

    const int ntiles = (N + 63) / 64;       // 1563

    prep_w<<<48, 256, 0, stream>>>(Wq, Wk, Wv, Wt);
    fat_gemm_sort<<<GRID, 384, 0, stream>>>(
        x, Wt, bq, bk, bv, qkv, ei, aux, regions, N, E, ntiles, NBC, CH);
    efine<<<NBC, 256, 0, stream>>>(regions, aux, P, sorted, N, NBC, CH);
    segment_attn<<<((size_t)N * 16 + 255) / 256, 256, 0, stream>>>(
        qkv, P, sorted, out, N, E);
}